// Round 1
// baseline (936.697 us; speedup 1.0000x reference)
//
#include <hip/hip_runtime.h>

// CAM (channel attention) for x:[16,512,64,64] fp32, gamma scalar.
// energy[b] = Q Q^T (Q = x reshaped [512,4096]); att = softmax(rowmin - e);
// out = gamma * (att @ Q) + x.

constexpr int Bb = 16;
constexpr int Cc = 512;
constexpr int NN = 4096;  // 64*64

#define TILE 64
#define KT 32
#define PAD 68  // k-major LDS row pitch (floats); 68%32=4 keeps banks spread, 16B-aligned rows

// ---------------- Kernel 1: energy[b] = Q[b] * Q[b]^T (fp32) ----------------
// grid (8,8,16), block 256 (16x16 threads, 4x4 outputs each), K-tile 32.
__global__ __launch_bounds__(256) void gram_kernel(const float* __restrict__ x,
                                                   float* __restrict__ energy) {
    __shared__ __align__(16) float As[KT][PAD];
    __shared__ __align__(16) float Bs[KT][PAD];
    const int b = blockIdx.z;
    const int rowTile = blockIdx.y * TILE;
    const int colTile = blockIdx.x * TILE;
    const float* Q = x + (size_t)b * Cc * NN;
    const int t = threadIdx.x;
    const int tx = t & 15;
    const int ty = t >> 4;
    float acc[4][4] = {};
    for (int k0 = 0; k0 < NN; k0 += KT) {
#pragma unroll
        for (int i = 0; i < 8; ++i) {
            int idx = t + i * 256;          // 2048 elements = 64 rows x 32 k
            int r = idx >> 5;
            int k = idx & 31;
            As[k][r] = Q[(size_t)(rowTile + r) * NN + k0 + k];
            Bs[k][r] = Q[(size_t)(colTile + r) * NN + k0 + k];
        }
        __syncthreads();
#pragma unroll
        for (int k = 0; k < KT; ++k) {
            float4 a = *reinterpret_cast<const float4*>(&As[k][ty * 4]);
            float4 bq = *reinterpret_cast<const float4*>(&Bs[k][tx * 4]);
            float av[4] = {a.x, a.y, a.z, a.w};
            float bv[4] = {bq.x, bq.y, bq.z, bq.w};
#pragma unroll
            for (int i = 0; i < 4; ++i)
#pragma unroll
                for (int j = 0; j < 4; ++j)
                    acc[i][j] = fmaf(av[i], bv[j], acc[i][j]);
        }
        __syncthreads();
    }
    float* E = energy + (size_t)b * Cc * Cc;
#pragma unroll
    for (int i = 0; i < 4; ++i) {
        const int rowG = rowTile + ty * 4 + i;
        float4 o;
        o.x = acc[i][0]; o.y = acc[i][1]; o.z = acc[i][2]; o.w = acc[i][3];
        *reinterpret_cast<float4*>(&E[(size_t)rowG * Cc + colTile + tx * 4]) = o;
    }
}

// ---------------- Kernel 2: in-place reverse-max softmax over rows ----------
// att[d] = exp(rowmin - e[d]) / sum_d exp(rowmin - e[d])
// (softmax(max - e) == this, exactly). One wave per 512-row; 4 rows/block.
__global__ __launch_bounds__(256) void softmax_kernel(float* __restrict__ energy) {
    const int wave = threadIdx.x >> 6;
    const int lane = threadIdx.x & 63;
    const int row = blockIdx.x * 4 + wave;  // in [0, B*C)
    float* E = energy + (size_t)row * Cc;
    float v[8];
    float mn = 3.4e38f;
#pragma unroll
    for (int i = 0; i < 8; ++i) {
        v[i] = E[lane + 64 * i];
        mn = fminf(mn, v[i]);
    }
#pragma unroll
    for (int off = 32; off; off >>= 1) mn = fminf(mn, __shfl_xor(mn, off, 64));
    float sum = 0.f;
#pragma unroll
    for (int i = 0; i < 8; ++i) {
        v[i] = __expf(mn - v[i]);
        sum += v[i];
    }
#pragma unroll
    for (int off = 32; off; off >>= 1) sum += __shfl_xor(sum, off, 64);
    const float inv = 1.0f / sum;
#pragma unroll
    for (int i = 0; i < 8; ++i) E[lane + 64 * i] = v[i] * inv;
}

// ---------------- Kernel 3: out = gamma * (att @ Q) + x ---------------------
// grid (64,8,16), block 256, 64x64 output tile, K over 512 channels.
__global__ __launch_bounds__(256) void pv_kernel(const float* __restrict__ x,
                                                 const float* __restrict__ att,
                                                 const float* __restrict__ gamma,
                                                 float* __restrict__ out) {
    __shared__ __align__(16) float As[KT][PAD];  // As[k][r] = att[rowTile+r][k0+k]
    __shared__ __align__(16) float Bs[KT][PAD];  // Bs[k][c] = Q[k0+k][colTile+c]
    const int b = blockIdx.z;
    const int rowTile = blockIdx.y * TILE;  // channel rows
    const int colTile = blockIdx.x * TILE;  // n cols
    const float* Q = x + (size_t)b * Cc * NN;
    const float* A = att + (size_t)b * Cc * Cc;
    const int t = threadIdx.x;
    const int tx = t & 15;
    const int ty = t >> 4;
    float acc[4][4] = {};
    for (int k0 = 0; k0 < Cc; k0 += KT) {
#pragma unroll
        for (int i = 0; i < 8; ++i) {
            int idx = t + i * 256;
            {
                int r = idx >> 5, k = idx & 31;
                As[k][r] = A[(size_t)(rowTile + r) * Cc + k0 + k];
            }
            {
                int k = idx >> 6, c = idx & 63;
                Bs[k][c] = Q[(size_t)(k0 + k) * NN + colTile + c];
            }
        }
        __syncthreads();
#pragma unroll
        for (int k = 0; k < KT; ++k) {
            float4 a = *reinterpret_cast<const float4*>(&As[k][ty * 4]);
            float4 bq = *reinterpret_cast<const float4*>(&Bs[k][tx * 4]);
            float av[4] = {a.x, a.y, a.z, a.w};
            float bv[4] = {bq.x, bq.y, bq.z, bq.w};
#pragma unroll
            for (int i = 0; i < 4; ++i)
#pragma unroll
                for (int j = 0; j < 4; ++j)
                    acc[i][j] = fmaf(av[i], bv[j], acc[i][j]);
        }
        __syncthreads();
    }
    const float g = gamma[0];
#pragma unroll
    for (int i = 0; i < 4; ++i) {
        const int rowG = rowTile + ty * 4 + i;
        const size_t base = (size_t)rowG * NN + colTile + tx * 4;
        const float4 xi = *reinterpret_cast<const float4*>(&Q[base]);
        float4 o;
        o.x = fmaf(g, acc[i][0], xi.x);
        o.y = fmaf(g, acc[i][1], xi.y);
        o.z = fmaf(g, acc[i][2], xi.z);
        o.w = fmaf(g, acc[i][3], xi.w);
        *reinterpret_cast<float4*>(&out[(size_t)b * Cc * NN + base]) = o;
    }
}

extern "C" void kernel_launch(void* const* d_in, const int* in_sizes, int n_in,
                              void* d_out, int out_size, void* d_ws, size_t ws_size,
                              hipStream_t stream) {
    const float* x = (const float*)d_in[0];
    const float* gamma = (const float*)d_in[1];
    float* out = (float*)d_out;
    float* energy = (float*)d_ws;  // B*C*C floats = 16.78 MB

    gram_kernel<<<dim3(Cc / TILE, Cc / TILE, Bb), 256, 0, stream>>>(x, energy);
    softmax_kernel<<<dim3(Bb * Cc / 4), 256, 0, stream>>>(energy);
    pv_kernel<<<dim3(NN / TILE, Cc / TILE, Bb), 256, 0, stream>>>(x, energy, gamma, out);
}

// Round 2
// 220.698 us; speedup vs baseline: 4.2442x; 4.2442x over previous
//
#include <hip/hip_runtime.h>

// CAM (channel attention): x [16,512,64,64] fp32, gamma scalar.
// energy[b] = Q Q^T; att = softmax(rowmax - energy) == exp(rowmin-e)/sum;
// out = gamma*(att@Q) + x.
// Fast path: fp16 MFMA GEMMs with swizzled fp16 copies of Q (Qh) and Q^T (QhT)
// in workspace. Fallback (small ws): round-1 fp32 vector path.

constexpr int Bb = 16;
constexpr int Cc = 512;
constexpr int NN = 4096;  // 64*64

typedef _Float16 half8 __attribute__((ext_vector_type(8)));
typedef float float4v __attribute__((ext_vector_type(4)));

// ---------------------------------------------------------------------------
// global->LDS direct copy, 16B per lane. LDS dest is wave-uniform base + lane*16.
__device__ inline void gld_lds16(const _Float16* g, _Float16* l) {
    __builtin_amdgcn_global_load_lds(
        (const __attribute__((address_space(1))) unsigned int*)g,
        (__attribute__((address_space(3))) unsigned int*)l, 16, 0, 0);
}

// ---------------------------------------------------------------------------
// Prep: x fp32 [b][512 d][4096 n] -> Qh fp16 [b][d][n] and QhT fp16 [b][n][d],
// both with 16B-chunk XOR swizzle within each 128B (64-half) segment:
// logical chunk c of row r stored at slot c ^ (r&7).
__global__ __launch_bounds__(256) void prep_kernel(const float* __restrict__ x,
                                                   _Float16* __restrict__ Qh,
                                                   _Float16* __restrict__ QhT) {
    __shared__ float T[64][65];
    const int b = blockIdx.z;
    const int n0 = blockIdx.x * 64;
    const int d0 = blockIdx.y * 64;
    const float* xb = x + ((size_t)b * Cc + d0) * NN + n0;
    const int tid = threadIdx.x;
#pragma unroll
    for (int i = 0; i < 4; ++i) {
        int lin = tid + i * 256;          // 1024 float4s = 64x64 floats
        int dr = lin >> 4;
        int c4 = (lin & 15) * 4;
        float4 v = *reinterpret_cast<const float4*>(&xb[(size_t)dr * NN + c4]);
        T[dr][c4 + 0] = v.x; T[dr][c4 + 1] = v.y;
        T[dr][c4 + 2] = v.z; T[dr][c4 + 3] = v.w;
    }
    __syncthreads();
    // Qh: rows are d, 8 chunks of 8 n each
#pragma unroll
    for (int i = 0; i < 2; ++i) {
        int widx = tid + i * 256;         // 512 chunks
        int dr = widx >> 3;
        int cn = widx & 7;
        half8 h;
#pragma unroll
        for (int j = 0; j < 8; ++j) h[j] = (_Float16)T[dr][cn * 8 + j];
        size_t dst = ((size_t)b * Cc + d0 + dr) * NN + n0 + ((cn ^ (dr & 7)) << 3);
        *reinterpret_cast<half8*>(&Qh[dst]) = h;
    }
    // QhT: rows are n, 8 chunks of 8 d each
#pragma unroll
    for (int i = 0; i < 2; ++i) {
        int widx = tid + i * 256;
        int nr = widx >> 3;
        int cd = widx & 7;
        half8 h;
#pragma unroll
        for (int j = 0; j < 8; ++j) h[j] = (_Float16)T[cd * 8 + j][nr];
        size_t dst = ((size_t)b * NN + n0 + nr) * Cc + d0 + ((cd ^ (nr & 7)) << 3);
        *reinterpret_cast<half8*>(&QhT[dst]) = h;
    }
}

// ---------------------------------------------------------------------------
// Shared MFMA GEMM template: D[m][n] = sum_k A[m][k]*B[n][k]  (both row-major,
// chunk-swizzled). 128x128 tile, BK=64, 4 waves (2x2 of 64x64), double-buffered.
// EPI 0: store fp32 D (energy). EPI 1: out = gamma*acc + x.
template <int EPI>
__global__ __launch_bounds__(256) void mfma_gemm(const _Float16* __restrict__ A,
                                                 const _Float16* __restrict__ Bp,
                                                 float* __restrict__ D,
                                                 const float* __restrict__ xres,
                                                 const float* __restrict__ gamma,
                                                 float* __restrict__ out,
                                                 int M, int N, int K) {
    __shared__ __align__(16) _Float16 sA[2][128 * 64];
    __shared__ __align__(16) _Float16 sB[2][128 * 64];
    const int b = blockIdx.z;
    const int rowTile = blockIdx.y * 128;
    const int colTile = blockIdx.x * 128;
    const _Float16* Ab = A + (size_t)b * M * K;
    const _Float16* Bb = Bp + (size_t)b * N * K;
    const int tid = threadIdx.x;

    float4v acc[4][4];
#pragma unroll
    for (int m = 0; m < 4; ++m)
#pragma unroll
        for (int n = 0; n < 4; ++n) acc[m][n] = (float4v){0.f, 0.f, 0.f, 0.f};

    auto stage = [&](int buf, int k0) {
#pragma unroll
        for (int i = 0; i < 4; ++i) {
            int idx = tid + i * 256;      // 1024 chunks per tile
            int r = idx >> 3;
            int c = idx & 7;
            gld_lds16(Ab + (size_t)(rowTile + r) * K + k0 + c * 8, &sA[buf][idx * 8]);
            gld_lds16(Bb + (size_t)(colTile + r) * K + k0 + c * 8, &sB[buf][idx * 8]);
        }
    };

    const int nt = K >> 6;
    stage(0, 0);
    __syncthreads();

    const int wid = tid >> 6, lane = tid & 63;
    const int wr = wid >> 1, wc = wid & 1;
    const int lr = lane & 15, q = lane >> 4;

    for (int t = 0; t < nt; ++t) {
        if (t + 1 < nt) stage((t + 1) & 1, (t + 1) << 6);
        const _Float16* cA = sA[t & 1];
        const _Float16* cB = sB[t & 1];
#pragma unroll
        for (int s = 0; s < 2; ++s) {
            half8 af[4], bf[4];
#pragma unroll
            for (int m = 0; m < 4; ++m) {
                int r = wr * 64 + m * 16 + lr;
                int c = (s * 4 + q) ^ (r & 7);
                af[m] = *reinterpret_cast<const half8*>(&cA[r * 64 + c * 8]);
            }
#pragma unroll
            for (int n = 0; n < 4; ++n) {
                int r = wc * 64 + n * 16 + lr;
                int c = (s * 4 + q) ^ (r & 7);
                bf[n] = *reinterpret_cast<const half8*>(&cB[r * 64 + c * 8]);
            }
#pragma unroll
            for (int m = 0; m < 4; ++m)
#pragma unroll
                for (int n = 0; n < 4; ++n)
                    acc[m][n] = __builtin_amdgcn_mfma_f32_16x16x32_f16(af[m], bf[n], acc[m][n], 0, 0, 0);
        }
        __syncthreads();
    }

    if (EPI == 0) {
        float* Db = D + (size_t)b * M * N;
#pragma unroll
        for (int m = 0; m < 4; ++m)
#pragma unroll
            for (int n = 0; n < 4; ++n)
#pragma unroll
                for (int e = 0; e < 4; ++e) {
                    int rg = rowTile + wr * 64 + m * 16 + q * 4 + e;
                    int cg = colTile + wc * 64 + n * 16 + lr;
                    Db[(size_t)rg * N + cg] = acc[m][n][e];
                }
    } else {
        const float g = gamma[0];
        const size_t base = (size_t)b * M * N;
#pragma unroll
        for (int m = 0; m < 4; ++m)
#pragma unroll
            for (int n = 0; n < 4; ++n)
#pragma unroll
                for (int e = 0; e < 4; ++e) {
                    int rg = rowTile + wr * 64 + m * 16 + q * 4 + e;
                    int cg = colTile + wc * 64 + n * 16 + lr;
                    size_t o = base + (size_t)rg * N + cg;
                    out[o] = fmaf(g, acc[m][n][e], xres[o]);
                }
    }
}

// ---------------------------------------------------------------------------
// Softmax: att = exp(rowmin - e)/sum (== softmax(rowmax - e)); fp32 energy in,
// fp16 att out, pre-swizzled (chunk lane stored at lane ^ (row&7)).
__global__ __launch_bounds__(256) void softmax_fp16(const float* __restrict__ energy,
                                                    _Float16* __restrict__ attH) {
    const int wave = threadIdx.x >> 6;
    const int lane = threadIdx.x & 63;
    const int row = blockIdx.x * 4 + wave;   // [0, B*C)
    const float* E = energy + (size_t)row * Cc;
    float v[8];
    float4 a = *reinterpret_cast<const float4*>(&E[lane * 8]);
    float4 c = *reinterpret_cast<const float4*>(&E[lane * 8 + 4]);
    v[0] = a.x; v[1] = a.y; v[2] = a.z; v[3] = a.w;
    v[4] = c.x; v[5] = c.y; v[6] = c.z; v[7] = c.w;
    float mn = v[0];
#pragma unroll
    for (int i = 1; i < 8; ++i) mn = fminf(mn, v[i]);
#pragma unroll
    for (int off = 32; off; off >>= 1) mn = fminf(mn, __shfl_xor(mn, off, 64));
    float sum = 0.f;
#pragma unroll
    for (int i = 0; i < 8; ++i) {
        v[i] = __expf(mn - v[i]);
        sum += v[i];
    }
#pragma unroll
    for (int off = 32; off; off >>= 1) sum += __shfl_xor(sum, off, 64);
    const float inv = 1.0f / sum;
    half8 h;
#pragma unroll
    for (int i = 0; i < 8; ++i) h[i] = (_Float16)(v[i] * inv);
    size_t dst = (size_t)row * Cc + ((lane ^ (row & 7)) << 3);
    *reinterpret_cast<half8*>(&attH[dst]) = h;
}

// ===========================================================================
// Fallback fp32 path (round-1, known good) for small workspace.
#define TILE 64
#define KT 32
#define PAD 68

__global__ __launch_bounds__(256) void gram_f32(const float* __restrict__ x,
                                                float* __restrict__ energy) {
    __shared__ __align__(16) float As[KT][PAD];
    __shared__ __align__(16) float Bs[KT][PAD];
    const int b = blockIdx.z;
    const int rowTile = blockIdx.y * TILE;
    const int colTile = blockIdx.x * TILE;
    const float* Q = x + (size_t)b * Cc * NN;
    const int t = threadIdx.x;
    const int tx = t & 15;
    const int ty = t >> 4;
    float acc[4][4] = {};
    for (int k0 = 0; k0 < NN; k0 += KT) {
#pragma unroll
        for (int i = 0; i < 8; ++i) {
            int idx = t + i * 256;
            int r = idx >> 5;
            int k = idx & 31;
            As[k][r] = Q[(size_t)(rowTile + r) * NN + k0 + k];
            Bs[k][r] = Q[(size_t)(colTile + r) * NN + k0 + k];
        }
        __syncthreads();
#pragma unroll
        for (int k = 0; k < KT; ++k) {
            float4 a = *reinterpret_cast<const float4*>(&As[k][ty * 4]);
            float4 bq = *reinterpret_cast<const float4*>(&Bs[k][tx * 4]);
            float av[4] = {a.x, a.y, a.z, a.w};
            float bv[4] = {bq.x, bq.y, bq.z, bq.w};
#pragma unroll
            for (int i = 0; i < 4; ++i)
#pragma unroll
                for (int j = 0; j < 4; ++j)
                    acc[i][j] = fmaf(av[i], bv[j], acc[i][j]);
        }
        __syncthreads();
    }
    float* E = energy + (size_t)b * Cc * Cc;
#pragma unroll
    for (int i = 0; i < 4; ++i) {
        const int rowG = rowTile + ty * 4 + i;
        float4 o;
        o.x = acc[i][0]; o.y = acc[i][1]; o.z = acc[i][2]; o.w = acc[i][3];
        *reinterpret_cast<float4*>(&E[(size_t)rowG * Cc + colTile + tx * 4]) = o;
    }
}

__global__ __launch_bounds__(256) void softmax_f32(float* __restrict__ energy) {
    const int wave = threadIdx.x >> 6;
    const int lane = threadIdx.x & 63;
    const int row = blockIdx.x * 4 + wave;
    float* E = energy + (size_t)row * Cc;
    float v[8];
    float mn = 3.4e38f;
#pragma unroll
    for (int i = 0; i < 8; ++i) {
        v[i] = E[lane + 64 * i];
        mn = fminf(mn, v[i]);
    }
#pragma unroll
    for (int off = 32; off; off >>= 1) mn = fminf(mn, __shfl_xor(mn, off, 64));
    float sum = 0.f;
#pragma unroll
    for (int i = 0; i < 8; ++i) {
        v[i] = __expf(mn - v[i]);
        sum += v[i];
    }
#pragma unroll
    for (int off = 32; off; off >>= 1) sum += __shfl_xor(sum, off, 64);
    const float inv = 1.0f / sum;
#pragma unroll
    for (int i = 0; i < 8; ++i) E[lane + 64 * i] = v[i] * inv;
}

__global__ __launch_bounds__(256) void pv_f32(const float* __restrict__ x,
                                              const float* __restrict__ att,
                                              const float* __restrict__ gamma,
                                              float* __restrict__ out) {
    __shared__ __align__(16) float As[KT][PAD];
    __shared__ __align__(16) float Bs[KT][PAD];
    const int b = blockIdx.z;
    const int rowTile = blockIdx.y * TILE;
    const int colTile = blockIdx.x * TILE;
    const float* Q = x + (size_t)b * Cc * NN;
    const float* A = att + (size_t)b * Cc * Cc;
    const int t = threadIdx.x;
    const int tx = t & 15;
    const int ty = t >> 4;
    float acc[4][4] = {};
    for (int k0 = 0; k0 < Cc; k0 += KT) {
#pragma unroll
        for (int i = 0; i < 8; ++i) {
            int idx = t + i * 256;
            {
                int r = idx >> 5, k = idx & 31;
                As[k][r] = A[(size_t)(rowTile + r) * Cc + k0 + k];
            }
            {
                int k = idx >> 6, c = idx & 63;
                Bs[k][c] = Q[(size_t)(k0 + k) * NN + colTile + c];
            }
        }
        __syncthreads();
#pragma unroll
        for (int k = 0; k < KT; ++k) {
            float4 a = *reinterpret_cast<const float4*>(&As[k][ty * 4]);
            float4 bq = *reinterpret_cast<const float4*>(&Bs[k][tx * 4]);
            float av[4] = {a.x, a.y, a.z, a.w};
            float bv[4] = {bq.x, bq.y, bq.z, bq.w};
#pragma unroll
            for (int i = 0; i < 4; ++i)
#pragma unroll
                for (int j = 0; j < 4; ++j)
                    acc[i][j] = fmaf(av[i], bv[j], acc[i][j]);
        }
        __syncthreads();
    }
    const float g = gamma[0];
#pragma unroll
    for (int i = 0; i < 4; ++i) {
        const int rowG = rowTile + ty * 4 + i;
        const size_t base = (size_t)rowG * NN + colTile + tx * 4;
        const float4 xi = *reinterpret_cast<const float4*>(&Q[base]);
        float4 o;
        o.x = fmaf(g, acc[i][0], xi.x);
        o.y = fmaf(g, acc[i][1], xi.y);
        o.z = fmaf(g, acc[i][2], xi.z);
        o.w = fmaf(g, acc[i][3], xi.w);
        *reinterpret_cast<float4*>(&out[(size_t)b * Cc * NN + base]) = o;
    }
}

// ===========================================================================
extern "C" void kernel_launch(void* const* d_in, const int* in_sizes, int n_in,
                              void* d_out, int out_size, void* d_ws, size_t ws_size,
                              hipStream_t stream) {
    const float* x = (const float*)d_in[0];
    const float* gamma = (const float*)d_in[1];
    float* out = (float*)d_out;

    // ws layout (fast path): Qh 64MB | QhT 64MB | energy 16MB | attH 8MB
    const size_t NQ = (size_t)Bb * Cc * NN;         // 33,554,432
    const size_t NE = (size_t)Bb * Cc * Cc;         // 4,194,304
    const size_t NEED = NQ * 2 * 2 + NE * 4 + NE * 2;  // 159,383,552 bytes

    if (ws_size >= NEED) {
        _Float16* Qh = (_Float16*)d_ws;
        _Float16* QhT = Qh + NQ;
        float* energy = (float*)(QhT + NQ);
        _Float16* attH = (_Float16*)(energy + NE);

        prep_kernel<<<dim3(NN / 64, Cc / 64, Bb), 256, 0, stream>>>(x, Qh, QhT);
        mfma_gemm<0><<<dim3(Cc / 128, Cc / 128, Bb), 256, 0, stream>>>(
            Qh, Qh, energy, nullptr, nullptr, nullptr, Cc, Cc, NN);
        softmax_fp16<<<dim3(Bb * Cc / 4), 256, 0, stream>>>(energy, attH);
        mfma_gemm<1><<<dim3(NN / 128, Cc / 128, Bb), 256, 0, stream>>>(
            attH, QhT, nullptr, x, gamma, out, Cc, NN, Cc);
    } else {
        float* energy = (float*)d_ws;  // 16.78 MB
        gram_f32<<<dim3(Cc / TILE, Cc / TILE, Bb), 256, 0, stream>>>(x, energy);
        softmax_f32<<<dim3(Bb * Cc / 4), 256, 0, stream>>>(energy);
        pv_f32<<<dim3(NN / TILE, Cc / TILE, Bb), 256, 0, stream>>>(x, energy, gamma, out);
    }
}

// Round 3
// 195.715 us; speedup vs baseline: 4.7860x; 1.1276x over previous
//
#include <hip/hip_runtime.h>

// CAM (channel attention): x [16,512,64,64] fp32, gamma scalar.
// energy[b] = Q Q^T; att = softmax(rowmax - energy) == exp(rowmin-e)/sum;
// out = gamma*(att@Q) + x.
// Fast path: fp16 MFMA GEMMs (8-wave 128x128 tiles, BK=64, dbuf LDS via
// global_load_lds, pre-swizzled global fp16 copies, XCD-aware block swizzle).
// Fallback (small ws): fp32 vector path.

constexpr int Bb = 16;
constexpr int Cc = 512;
constexpr int NN = 4096;  // 64*64

typedef _Float16 half8 __attribute__((ext_vector_type(8)));
typedef float float4v __attribute__((ext_vector_type(4)));

// ---------------------------------------------------------------------------
__device__ inline void gld_lds16(const _Float16* g, _Float16* l) {
    __builtin_amdgcn_global_load_lds(
        (const __attribute__((address_space(1))) unsigned int*)g,
        (__attribute__((address_space(3))) unsigned int*)l, 16, 0, 0);
}

// ---------------------------------------------------------------------------
// Prep: x fp32 [b][512 d][4096 n] -> Qh fp16 [b][d][n] and QhT fp16 [b][n][d],
// 16B-chunk XOR swizzle within each 64-half segment: chunk c of row r stored
// at slot c ^ (r&7).
__global__ __launch_bounds__(256) void prep_kernel(const float* __restrict__ x,
                                                   _Float16* __restrict__ Qh,
                                                   _Float16* __restrict__ QhT) {
    __shared__ float T[64][65];
    const int b = blockIdx.z;
    const int n0 = blockIdx.x * 64;
    const int d0 = blockIdx.y * 64;
    const float* xb = x + ((size_t)b * Cc + d0) * NN + n0;
    const int tid = threadIdx.x;
#pragma unroll
    for (int i = 0; i < 4; ++i) {
        int lin = tid + i * 256;
        int dr = lin >> 4;
        int c4 = (lin & 15) * 4;
        float4 v = *reinterpret_cast<const float4*>(&xb[(size_t)dr * NN + c4]);
        T[dr][c4 + 0] = v.x; T[dr][c4 + 1] = v.y;
        T[dr][c4 + 2] = v.z; T[dr][c4 + 3] = v.w;
    }
    __syncthreads();
#pragma unroll
    for (int i = 0; i < 2; ++i) {
        int widx = tid + i * 256;
        int dr = widx >> 3;
        int cn = widx & 7;
        half8 h;
#pragma unroll
        for (int j = 0; j < 8; ++j) h[j] = (_Float16)T[dr][cn * 8 + j];
        size_t dst = ((size_t)b * Cc + d0 + dr) * NN + n0 + ((cn ^ (dr & 7)) << 3);
        *reinterpret_cast<half8*>(&Qh[dst]) = h;
    }
#pragma unroll
    for (int i = 0; i < 2; ++i) {
        int widx = tid + i * 256;
        int nr = widx >> 3;
        int cd = widx & 7;
        half8 h;
#pragma unroll
        for (int j = 0; j < 8; ++j) h[j] = (_Float16)T[cd * 8 + j][nr];
        size_t dst = ((size_t)b * NN + n0 + nr) * Cc + d0 + ((cd ^ (nr & 7)) << 3);
        *reinterpret_cast<half8*>(&QhT[dst]) = h;
    }
}

// ---------------------------------------------------------------------------
// 8-wave MFMA GEMM: D[m][n] = sum_k A[m][k]*B[n][k] (both row-major, chunk-
// swizzled). 128x128 tile, BK=64, 8 waves (2x4, each 64x32), double-buffered.
// 1D grid with XCD swizzle; BPB = blocks per batch (must have y*x tiles = BPB).
// EPI 0: store fp32 D (energy). EPI 1: out = gamma*acc + xres.
template <int EPI, int BPB, int NTX>
__global__ __launch_bounds__(512, 4) void mfma_gemm(const _Float16* __restrict__ A,
                                                    const _Float16* __restrict__ Bp,
                                                    float* __restrict__ D,
                                                    const float* __restrict__ xres,
                                                    const float* __restrict__ gamma,
                                                    float* __restrict__ out,
                                                    int M, int N, int K) {
    __shared__ __align__(16) _Float16 sA[2][128 * 64];
    __shared__ __align__(16) _Float16 sB[2][128 * 64];
    // XCD-aware bijective swizzle: grid is a multiple of 8.
    const int L = blockIdx.x;
    const int t0 = (L & 7) * ((BPB * Bb) >> 3) + (L >> 3);
    const int b = t0 / BPB;
    const int rem = t0 % BPB;
    const int rowTile = (rem / NTX) * 128;
    const int colTile = (rem % NTX) * 128;

    const _Float16* Ab = A + (size_t)b * M * K;
    const _Float16* Bbp = Bp + (size_t)b * N * K;
    const int tid = threadIdx.x;

    float4v acc[4][2];
#pragma unroll
    for (int m = 0; m < 4; ++m)
#pragma unroll
        for (int n = 0; n < 2; ++n) acc[m][n] = (float4v){0.f, 0.f, 0.f, 0.f};

    auto stage = [&](int buf, int k0) {
#pragma unroll
        for (int i = 0; i < 2; ++i) {
            int idx = tid + i * 512;      // 1024 chunks per tile
            int r = idx >> 3;
            int c = idx & 7;
            gld_lds16(Ab + (size_t)(rowTile + r) * K + k0 + c * 8, &sA[buf][idx * 8]);
            gld_lds16(Bbp + (size_t)(colTile + r) * K + k0 + c * 8, &sB[buf][idx * 8]);
        }
    };

    const int nt = K >> 6;
    stage(0, 0);
    __syncthreads();

    const int wid = tid >> 6, lane = tid & 63;
    const int wr = wid >> 2, wc = wid & 3;   // 2 x 4 waves, each 64(m) x 32(n)
    const int lr = lane & 15, q = lane >> 4;

    for (int t = 0; t < nt; ++t) {
        if (t + 1 < nt) stage((t + 1) & 1, (t + 1) << 6);
        const _Float16* cA = sA[t & 1];
        const _Float16* cB = sB[t & 1];
#pragma unroll
        for (int s = 0; s < 2; ++s) {
            half8 af[4], bf[2];
#pragma unroll
            for (int m = 0; m < 4; ++m) {
                int r = wr * 64 + m * 16 + lr;
                int c = (s * 4 + q) ^ (r & 7);
                af[m] = *reinterpret_cast<const half8*>(&cA[r * 64 + c * 8]);
            }
#pragma unroll
            for (int n = 0; n < 2; ++n) {
                int r = wc * 32 + n * 16 + lr;
                int c = (s * 4 + q) ^ (r & 7);
                bf[n] = *reinterpret_cast<const half8*>(&cB[r * 64 + c * 8]);
            }
#pragma unroll
            for (int m = 0; m < 4; ++m)
#pragma unroll
                for (int n = 0; n < 2; ++n)
                    acc[m][n] = __builtin_amdgcn_mfma_f32_16x16x32_f16(af[m], bf[n], acc[m][n], 0, 0, 0);
        }
        __syncthreads();
    }

    if (EPI == 0) {
        float* Db = D + (size_t)b * M * N;
#pragma unroll
        for (int m = 0; m < 4; ++m)
#pragma unroll
            for (int n = 0; n < 2; ++n)
#pragma unroll
                for (int e = 0; e < 4; ++e) {
                    int rg = rowTile + wr * 64 + m * 16 + q * 4 + e;
                    int cg = colTile + wc * 32 + n * 16 + lr;
                    Db[(size_t)rg * N + cg] = acc[m][n][e];
                }
    } else {
        const float g = gamma[0];
        const size_t base = (size_t)b * M * N;
#pragma unroll
        for (int m = 0; m < 4; ++m)
#pragma unroll
            for (int n = 0; n < 2; ++n)
#pragma unroll
                for (int e = 0; e < 4; ++e) {
                    int rg = rowTile + wr * 64 + m * 16 + q * 4 + e;
                    int cg = colTile + wc * 32 + n * 16 + lr;
                    size_t o = base + (size_t)rg * N + cg;
                    out[o] = fmaf(g, acc[m][n][e], xres[o]);
                }
    }
}

// ---------------------------------------------------------------------------
// Softmax: att = exp(rowmin - e)/sum; fp32 energy in, fp16 att out,
// pre-swizzled (chunk lane stored at lane ^ (row&7)).
__global__ __launch_bounds__(256) void softmax_fp16(const float* __restrict__ energy,
                                                    _Float16* __restrict__ attH) {
    const int wave = threadIdx.x >> 6;
    const int lane = threadIdx.x & 63;
    const int row = blockIdx.x * 4 + wave;
    const float* E = energy + (size_t)row * Cc;
    float v[8];
    float4 a = *reinterpret_cast<const float4*>(&E[lane * 8]);
    float4 c = *reinterpret_cast<const float4*>(&E[lane * 8 + 4]);
    v[0] = a.x; v[1] = a.y; v[2] = a.z; v[3] = a.w;
    v[4] = c.x; v[5] = c.y; v[6] = c.z; v[7] = c.w;
    float mn = v[0];
#pragma unroll
    for (int i = 1; i < 8; ++i) mn = fminf(mn, v[i]);
#pragma unroll
    for (int off = 32; off; off >>= 1) mn = fminf(mn, __shfl_xor(mn, off, 64));
    float sum = 0.f;
#pragma unroll
    for (int i = 0; i < 8; ++i) {
        v[i] = __expf(mn - v[i]);
        sum += v[i];
    }
#pragma unroll
    for (int off = 32; off; off >>= 1) sum += __shfl_xor(sum, off, 64);
    const float inv = 1.0f / sum;
    half8 h;
#pragma unroll
    for (int i = 0; i < 8; ++i) h[i] = (_Float16)(v[i] * inv);
    size_t dst = (size_t)row * Cc + ((lane ^ (row & 7)) << 3);
    *reinterpret_cast<half8*>(&attH[dst]) = h;
}

// ===========================================================================
// Fallback fp32 path (known good) for small workspace.
#define TILE 64
#define KT 32
#define PAD 68

__global__ __launch_bounds__(256) void gram_f32(const float* __restrict__ x,
                                                float* __restrict__ energy) {
    __shared__ __align__(16) float As[KT][PAD];
    __shared__ __align__(16) float Bs[KT][PAD];
    const int b = blockIdx.z;
    const int rowTile = blockIdx.y * TILE;
    const int colTile = blockIdx.x * TILE;
    const float* Q = x + (size_t)b * Cc * NN;
    const int t = threadIdx.x;
    const int tx = t & 15;
    const int ty = t >> 4;
    float acc[4][4] = {};
    for (int k0 = 0; k0 < NN; k0 += KT) {
#pragma unroll
        for (int i = 0; i < 8; ++i) {
            int idx = t + i * 256;
            int r = idx >> 5;
            int k = idx & 31;
            As[k][r] = Q[(size_t)(rowTile + r) * NN + k0 + k];
            Bs[k][r] = Q[(size_t)(colTile + r) * NN + k0 + k];
        }
        __syncthreads();
#pragma unroll
        for (int k = 0; k < KT; ++k) {
            float4 a = *reinterpret_cast<const float4*>(&As[k][ty * 4]);
            float4 bq = *reinterpret_cast<const float4*>(&Bs[k][tx * 4]);
            float av[4] = {a.x, a.y, a.z, a.w};
            float bv[4] = {bq.x, bq.y, bq.z, bq.w};
#pragma unroll
            for (int i = 0; i < 4; ++i)
#pragma unroll
                for (int j = 0; j < 4; ++j)
                    acc[i][j] = fmaf(av[i], bv[j], acc[i][j]);
        }
        __syncthreads();
    }
    float* E = energy + (size_t)b * Cc * Cc;
#pragma unroll
    for (int i = 0; i < 4; ++i) {
        const int rowG = rowTile + ty * 4 + i;
        float4 o;
        o.x = acc[i][0]; o.y = acc[i][1]; o.z = acc[i][2]; o.w = acc[i][3];
        *reinterpret_cast<float4*>(&E[(size_t)rowG * Cc + colTile + tx * 4]) = o;
    }
}

__global__ __launch_bounds__(256) void softmax_f32(float* __restrict__ energy) {
    const int wave = threadIdx.x >> 6;
    const int lane = threadIdx.x & 63;
    const int row = blockIdx.x * 4 + wave;
    float* E = energy + (size_t)row * Cc;
    float v[8];
    float mn = 3.4e38f;
#pragma unroll
    for (int i = 0; i < 8; ++i) {
        v[i] = E[lane + 64 * i];
        mn = fminf(mn, v[i]);
    }
#pragma unroll
    for (int off = 32; off; off >>= 1) mn = fminf(mn, __shfl_xor(mn, off, 64));
    float sum = 0.f;
#pragma unroll
    for (int i = 0; i < 8; ++i) {
        v[i] = __expf(mn - v[i]);
        sum += v[i];
    }
#pragma unroll
    for (int off = 32; off; off >>= 1) sum += __shfl_xor(sum, off, 64);
    const float inv = 1.0f / sum;
#pragma unroll
    for (int i = 0; i < 8; ++i) E[lane + 64 * i] = v[i] * inv;
}

__global__ __launch_bounds__(256) void pv_f32(const float* __restrict__ x,
                                              const float* __restrict__ att,
                                              const float* __restrict__ gamma,
                                              float* __restrict__ out) {
    __shared__ __align__(16) float As[KT][PAD];
    __shared__ __align__(16) float Bs[KT][PAD];
    const int b = blockIdx.z;
    const int rowTile = blockIdx.y * TILE;
    const int colTile = blockIdx.x * TILE;
    const float* Q = x + (size_t)b * Cc * NN;
    const float* A = att + (size_t)b * Cc * Cc;
    const int t = threadIdx.x;
    const int tx = t & 15;
    const int ty = t >> 4;
    float acc[4][4] = {};
    for (int k0 = 0; k0 < Cc; k0 += KT) {
#pragma unroll
        for (int i = 0; i < 8; ++i) {
            int idx = t + i * 256;
            {
                int r = idx >> 5, k = idx & 31;
                As[k][r] = A[(size_t)(rowTile + r) * Cc + k0 + k];
            }
            {
                int k = idx >> 6, c = idx & 63;
                Bs[k][c] = Q[(size_t)(k0 + k) * NN + colTile + c];
            }
        }
        __syncthreads();
#pragma unroll
        for (int k = 0; k < KT; ++k) {
            float4 a = *reinterpret_cast<const float4*>(&As[k][ty * 4]);
            float4 bq = *reinterpret_cast<const float4*>(&Bs[k][tx * 4]);
            float av[4] = {a.x, a.y, a.z, a.w};
            float bv[4] = {bq.x, bq.y, bq.z, bq.w};
#pragma unroll
            for (int i = 0; i < 4; ++i)
#pragma unroll
                for (int j = 0; j < 4; ++j)
                    acc[i][j] = fmaf(av[i], bv[j], acc[i][j]);
        }
        __syncthreads();
    }
    const float g = gamma[0];
#pragma unroll
    for (int i = 0; i < 4; ++i) {
        const int rowG = rowTile + ty * 4 + i;
        const size_t base = (size_t)rowG * NN + colTile + tx * 4;
        const float4 xi = *reinterpret_cast<const float4*>(&Q[base]);
        float4 o;
        o.x = fmaf(g, acc[i][0], xi.x);
        o.y = fmaf(g, acc[i][1], xi.y);
        o.z = fmaf(g, acc[i][2], xi.z);
        o.w = fmaf(g, acc[i][3], xi.w);
        *reinterpret_cast<float4*>(&out[(size_t)b * Cc * NN + base]) = o;
    }
}

// ===========================================================================
extern "C" void kernel_launch(void* const* d_in, const int* in_sizes, int n_in,
                              void* d_out, int out_size, void* d_ws, size_t ws_size,
                              hipStream_t stream) {
    const float* x = (const float*)d_in[0];
    const float* gamma = (const float*)d_in[1];
    float* out = (float*)d_out;

    const size_t NQ = (size_t)Bb * Cc * NN;
    const size_t NE = (size_t)Bb * Cc * Cc;
    const size_t NEED = NQ * 2 * 2 + NE * 4 + NE * 2;  // 159,383,552 bytes

    if (ws_size >= NEED) {
        _Float16* Qh = (_Float16*)d_ws;
        _Float16* QhT = Qh + NQ;
        float* energy = (float*)(QhT + NQ);
        _Float16* attH = (_Float16*)(energy + NE);

        prep_kernel<<<dim3(NN / 64, Cc / 64, Bb), 256, 0, stream>>>(x, Qh, QhT);
        // gram: M=N=512 -> 4x4 tiles = 16 blocks/batch, 256 total
        mfma_gemm<0, 16, 4><<<dim3(16 * Bb), 512, 0, stream>>>(
            Qh, Qh, energy, nullptr, nullptr, nullptr, Cc, Cc, NN);
        softmax_fp16<<<dim3(Bb * Cc / 4), 256, 0, stream>>>(energy, attH);
        // pv: M=512, N=4096 -> 4x32 tiles = 128 blocks/batch, 2048 total
        mfma_gemm<1, 128, 32><<<dim3(128 * Bb), 512, 0, stream>>>(
            attH, QhT, nullptr, x, gamma, out, Cc, NN, Cc);
    } else {
        float* energy = (float*)d_ws;
        gram_f32<<<dim3(Cc / TILE, Cc / TILE, Bb), 256, 0, stream>>>(x, energy);
        softmax_f32<<<dim3(Bb * Cc / 4), 256, 0, stream>>>(energy);
        pv_f32<<<dim3(NN / TILE, Cc / TILE, Bb), 256, 0, stream>>>(x, energy, gamma, out);
    }
}